// Round 17
// baseline (215.495 us; speedup 1.0000x reference)
//
#include <hip/hip_runtime.h>

typedef __attribute__((ext_vector_type(8))) short bf16x8;
typedef __attribute__((ext_vector_type(4))) float f32x4;
typedef __attribute__((ext_vector_type(2))) float f32x2;

#define N_NODES 10000
#define N_EDGES 320000
#define DIM_IN  256
#define DD      128
#define HH      4
#define HD      512
#define GG      64

__device__ inline f32x2 pk_add(f32x2 a, f32x2 b) {
  f32x2 d;
  asm("v_pk_add_f32 %0, %1, %2" : "=v"(d) : "v"(a), "v"(b));
  return d;
}
__device__ inline void pk_fma_acc(f32x2& acc, f32x2 a, f32x2 b) {
  asm("v_pk_fma_f32 %0, %1, %2, %0" : "+v"(acc) : "v"(a), "v"(b));
}

// ---------------- CSR build ----------------
__global__ void hist_kernel(const int* __restrict__ dst, int* __restrict__ cnt) {
  int e = blockIdx.x * 256 + threadIdx.x;
  atomicAdd(&cnt[dst[e]], 1);
}

__global__ void scan_kernel(const int* __restrict__ cnt, int* __restrict__ row_off) {
  __shared__ int part[1024];
  int t = threadIdx.x;
  int base = t * 10;
  int s = 0;
#pragma unroll
  for (int i = 0; i < 10; i++) { int idx = base + i; if (idx < N_NODES) s += cnt[idx]; }
  part[t] = s;
  __syncthreads();
  for (int off = 1; off < 1024; off <<= 1) {
    int v = (t >= off) ? part[t - off] : 0;
    __syncthreads();
    part[t] += v;
    __syncthreads();
  }
  int run = part[t] - s;
  for (int i = 0; i < 10; i++) {
    int idx = base + i;
    if (idx < N_NODES) { row_off[idx] = run; run += cnt[idx]; }
  }
  if (t == 1023) row_off[N_NODES] = part[1023];
}

__global__ void scatter_kernel(const int* __restrict__ src, const int* __restrict__ dst,
                               const int* __restrict__ row_off,
                               int* __restrict__ fill, int* __restrict__ srcl) {
  int e = blockIdx.x * 256 + threadIdx.x;
  int d = dst[e];
  int pos = row_off[d] + atomicAdd(&fill[d], 1);
  srcl[pos] = src[e];
}

// ---------------- split-precision helpers ----------------
__device__ inline void split4(float4 v, ushort4& h, ushort4& l) {
  uint bx = __float_as_uint(v.x), by = __float_as_uint(v.y);
  uint bz = __float_as_uint(v.z), bw = __float_as_uint(v.w);
  float rx = v.x - __uint_as_float(bx & 0xFFFF0000u);
  float ry = v.y - __uint_as_float(by & 0xFFFF0000u);
  float rz = v.z - __uint_as_float(bz & 0xFFFF0000u);
  float rw = v.w - __uint_as_float(bw & 0xFFFF0000u);
  h.x = (unsigned short)(bx >> 16); h.y = (unsigned short)(by >> 16);
  h.z = (unsigned short)(bz >> 16); h.w = (unsigned short)(bw >> 16);
  l.x = (unsigned short)(__float_as_uint(rx) >> 16);
  l.y = (unsigned short)(__float_as_uint(ry) >> 16);
  l.z = (unsigned short)(__float_as_uint(rz) >> 16);
  l.w = (unsigned short)(__float_as_uint(rw) >> 16);
}

// row-major fp32 [M][K] -> bf16 hi/lo [M][K]
__global__ __launch_bounds__(256) void split_rm(const float* __restrict__ in,
                                                ushort* __restrict__ oh,
                                                ushort* __restrict__ ol, int n4) {
  int i = blockIdx.x * 256 + threadIdx.x;
  if (i >= n4) return;
  float4 v = ((const float4*)in)[i];
  ushort4 h, l;
  split4(v, h, l);
  ((ushort4*)oh)[i] = h;
  ((ushort4*)ol)[i] = l;
}

// two fp32 [K][N] -> bf16 hi/lo transposed [N][K]; blockIdx.y selects matrix
__global__ __launch_bounds__(256) void split_tr2(
    const float* __restrict__ in0, ushort* __restrict__ oh0, ushort* __restrict__ ol0,
    const float* __restrict__ in1, ushort* __restrict__ oh1, ushort* __restrict__ ol1,
    int K, int N, int lgN) {
  const float* in = blockIdx.y ? in1 : in0;
  ushort* oh = blockIdx.y ? oh1 : oh0;
  ushort* ol = blockIdx.y ? ol1 : ol0;
  int id = blockIdx.x * 256 + threadIdx.x;
  int n = id & (N - 1);
  int kq = id >> lgN;
  if (kq >= (K >> 2)) return;
  int k = kq * 4;
  float4 v;
  v.x = in[(size_t)(k + 0) * N + n];
  v.y = in[(size_t)(k + 1) * N + n];
  v.z = in[(size_t)(k + 2) * N + n];
  v.w = in[(size_t)(k + 3) * N + n];
  ushort4 h, l;
  split4(v, h, l);
  *(ushort4*)(oh + (size_t)n * K + k) = h;
  *(ushort4*)(ol + (size_t)n * K + k) = l;
}

// ---------------- dual GEMM via bf16x3 MFMA (register-prefetch pipelined) ------
template <int K, int NCOL>
__global__ __launch_bounds__(256) void dual_gemm_mfma(
    const ushort* __restrict__ Ahg, const ushort* __restrict__ Alg,
    const ushort* __restrict__ B1hg, const ushort* __restrict__ B1lg,
    const float* __restrict__ bias1,
    const ushort* __restrict__ B2hg, const ushort* __restrict__ B2lg,
    const float* __restrict__ bias2,
    float* __restrict__ C1, float* __restrict__ C2, int M) {
  __shared__ ushort Ah[64][40], Al[64][40];
  __shared__ ushort B1h[64][40], B1l[64][40], B2h[64][40], B2l[64][40];
  int t = threadIdx.x;
  int lane = t & 63, wv = t >> 6;
  int wr = wv >> 1, wc = wv & 1;
  int l15 = lane & 15, l16 = lane >> 4;
  int col0 = blockIdx.x * 64, m0 = blockIdx.y * 64;

  int sr = t >> 2;           // staging row (A) / col (B): 0..63
  int sk = (t & 3) * 8;      // staging k offset: 0,8,16,24
  bool arow_ok = (m0 + sr) < M;
  const ushort* pAh = Ahg + (size_t)(m0 + sr) * K + sk;
  const ushort* pAl = Alg + (size_t)(m0 + sr) * K + sk;
  const ushort* pB1h = B1hg + (size_t)(col0 + sr) * K + sk;
  const ushort* pB1l = B1lg + (size_t)(col0 + sr) * K + sk;
  const ushort* pB2h = B2hg + (size_t)(col0 + sr) * K + sk;
  const ushort* pB2l = B2lg + (size_t)(col0 + sr) * K + sk;

  f32x4 zero = {0.f, 0.f, 0.f, 0.f};
  f32x4 acc1[2][2], acc2[2][2];
#pragma unroll
  for (int i = 0; i < 2; i++)
#pragma unroll
    for (int j = 0; j < 2; j++) { acc1[i][j] = zero; acc2[i][j] = zero; }

  uint4 vah, val, v1h, v1l, v2h, v2l;
#define LOADK(KO)                                                            \
  vah = arow_ok ? *(const uint4*)(pAh + (KO)) : make_uint4(0u, 0u, 0u, 0u);  \
  val = arow_ok ? *(const uint4*)(pAl + (KO)) : make_uint4(0u, 0u, 0u, 0u);  \
  v1h = *(const uint4*)(pB1h + (KO));                                        \
  v1l = *(const uint4*)(pB1l + (KO));                                        \
  v2h = *(const uint4*)(pB2h + (KO));                                        \
  v2l = *(const uint4*)(pB2l + (KO));
  LOADK(0)
  for (int k0 = 0; k0 < K; k0 += 32) {
    __syncthreads();
    *(uint4*)&Ah[sr][sk] = vah;
    *(uint4*)&Al[sr][sk] = val;
    *(uint4*)&B1h[sr][sk] = v1h;
    *(uint4*)&B1l[sr][sk] = v1l;
    *(uint4*)&B2h[sr][sk] = v2h;
    *(uint4*)&B2l[sr][sk] = v2l;
    __syncthreads();
    if (k0 + 32 < K) { LOADK(k0 + 32) }   // issue next-tile loads before MFMA
#pragma unroll
    for (int cb = 0; cb < 2; cb++) {
      int bc = wc * 32 + cb * 16 + l15;
      bf16x8 b1hf = *(const bf16x8*)&B1h[bc][l16 * 8];
      bf16x8 b1lf = *(const bf16x8*)&B1l[bc][l16 * 8];
      bf16x8 b2hf = *(const bf16x8*)&B2h[bc][l16 * 8];
      bf16x8 b2lf = *(const bf16x8*)&B2l[bc][l16 * 8];
#pragma unroll
      for (int rb = 0; rb < 2; rb++) {
        int arw = wr * 32 + rb * 16 + l15;
        bf16x8 ahf = *(const bf16x8*)&Ah[arw][l16 * 8];
        bf16x8 alf = *(const bf16x8*)&Al[arw][l16 * 8];
        acc1[rb][cb] = __builtin_amdgcn_mfma_f32_16x16x32_bf16(ahf, b1hf, acc1[rb][cb], 0, 0, 0);
        acc1[rb][cb] = __builtin_amdgcn_mfma_f32_16x16x32_bf16(ahf, b1lf, acc1[rb][cb], 0, 0, 0);
        acc1[rb][cb] = __builtin_amdgcn_mfma_f32_16x16x32_bf16(alf, b1hf, acc1[rb][cb], 0, 0, 0);
        acc2[rb][cb] = __builtin_amdgcn_mfma_f32_16x16x32_bf16(ahf, b2hf, acc2[rb][cb], 0, 0, 0);
        acc2[rb][cb] = __builtin_amdgcn_mfma_f32_16x16x32_bf16(ahf, b2lf, acc2[rb][cb], 0, 0, 0);
        acc2[rb][cb] = __builtin_amdgcn_mfma_f32_16x16x32_bf16(alf, b2hf, acc2[rb][cb], 0, 0, 0);
      }
    }
  }
#undef LOADK
#pragma unroll
  for (int rb = 0; rb < 2; rb++) {
#pragma unroll
    for (int cb = 0; cb < 2; cb++) {
      int row = m0 + wr * 32 + rb * 16 + l16 * 4;
      int col = col0 + wc * 32 + cb * 16 + l15;
      float bb1 = bias1[col], bb2 = bias2[col];
#pragma unroll
      for (int rr = 0; rr < 4; rr++) {
        if (row + rr < M) {
          C1[(size_t)(row + rr) * NCOL + col] = acc1[rb][cb][rr] + bb1;
          C2[(size_t)(row + rr) * NCOL + col] = acc2[rb][cb][rr] + bb2;
        }
      }
    }
  }
}

// ---------------- layer 1 fused: XCD-pinned head-slices, packed fp32 ----------
// Launched TWICE (slice_base 0 and 2); grid 2N, 64-thr 1-wave blocks:
// block b -> slice = slice_base + (b & 1), node = b >> 1 (parity-stride-8 keeps
// one slice per XCD). Wave = 4 x 16-lane groups; group owns one edge; lane
// covers 8 floats. e = u+hd via v_pk_add_f32; acc += wg*u via v_pk_fma_f32;
// leaky(x) = 0.6x + 0.4|x| scalar (abs = free modifier).
// EXEC-SAFE unconditional __shfl (clamped index).
__global__ __launch_bounds__(64) void fused_gat1(
    const float* __restrict__ hs, const float* __restrict__ hd,
    const float* __restrict__ attn, const int* __restrict__ row_off,
    const int* __restrict__ srcl,
    ushort* __restrict__ outh, ushort* __restrict__ outl, int slice_base) {
  int lane = threadIdx.x;
  int slice = slice_base + (blockIdx.x & 1);
  int v = blockIdx.x >> 1;
  int grp = lane >> 4, sl = lane & 15;
  int off = slice * 128 + sl * 8;
  int start = row_off[v];
  int deg = row_off[v + 1] - start;

  const float* ap = attn + off;
  const float* hp = hd + (size_t)v * HD + off;
  float4 a0 = *(const float4*)ap, a1 = *(const float4*)(ap + 4);
  float4 g0 = *(const float4*)hp, g1 = *(const float4*)(hp + 4);
  float areg[8] = {a0.x, a0.y, a0.z, a0.w, a1.x, a1.y, a1.z, a1.w};
  float a6[8], a4[8];
#pragma unroll
  for (int j = 0; j < 8; j++) { a6[j] = 0.6f * areg[j]; a4[j] = 0.4f * areg[j]; }
  f32x2 hd2[4] = {{g0.x, g0.y}, {g0.z, g0.w}, {g1.x, g1.y}, {g1.z, g1.w}};
  const float* hsl = hs + off;

  float ssum = 0.f;
  f32x2 acc2[4] = {{0.f, 0.f}, {0.f, 0.f}, {0.f, 0.f}, {0.f, 0.f}};

  for (int base = 0; base < deg; base += 64) {
    int nc = deg - base; nc = nc < 64 ? nc : 64;
    // one coalesced index load per 64-edge chunk
    int myidx = (lane < nc) ? srcl[start + base + lane] : 0;

    // 2-deep pipeline: buffer A = edges i0+grp, buffer B = edges i0+4+grp
    float4 cAa = {0,0,0,0}, cAb = {0,0,0,0}, cBa = {0,0,0,0}, cBb = {0,0,0,0};
    {
      int eA = grp, eB = grp + 4;
      int idxA = __shfl(myidx, eA < nc ? eA : 0);   // unconditional shfl
      int idxB = __shfl(myidx, eB < nc ? eB : 0);   // unconditional shfl
      if (eA < nc) { const float* p = hsl + (size_t)idxA * HD; cAa = *(const float4*)p; cAb = *(const float4*)(p + 4); }
      if (eB < nc) { const float* p = hsl + (size_t)idxB * HD; cBa = *(const float4*)p; cBb = *(const float4*)(p + 4); }
    }

    for (int i0 = 0; i0 < nc; i0 += 8) {
#define GAT1_STEP(S, CA, CB)                                                   \
      { int e = i0 + 4 * S + grp;                                              \
        int nx = i0 + 8 + 4 * S + grp;                                         \
        int nidx = __shfl(myidx, nx < nc ? nx : 0);  /* unconditional shfl */  \
        bool vld = e < nc;                                                     \
        f32x2 u0 = {CA.x, CA.y}, u1 = {CA.z, CA.w};                            \
        f32x2 u2 = {CB.x, CB.y}, u3 = {CB.z, CB.w};                            \
        if (nx < nc) {                                                         \
          const float* p = hsl + (size_t)nidx * HD;                            \
          CA = *(const float4*)p; CB = *(const float4*)(p + 4);                \
        }                                                                      \
        f32x2 e0 = pk_add(u0, hd2[0]);                                         \
        f32x2 e1 = pk_add(u1, hd2[1]);                                         \
        f32x2 e2 = pk_add(u2, hd2[2]);                                         \
        f32x2 e3 = pk_add(u3, hd2[3]);                                         \
        float part = 0.f;                                                      \
        part = fmaf(e0.x, a6[0], part); part = fmaf(fabsf(e0.x), a4[0], part); \
        part = fmaf(e0.y, a6[1], part); part = fmaf(fabsf(e0.y), a4[1], part); \
        part = fmaf(e1.x, a6[2], part); part = fmaf(fabsf(e1.x), a4[2], part); \
        part = fmaf(e1.y, a6[3], part); part = fmaf(fabsf(e1.y), a4[3], part); \
        part = fmaf(e2.x, a6[4], part); part = fmaf(fabsf(e2.x), a4[4], part); \
        part = fmaf(e2.y, a6[5], part); part = fmaf(fabsf(e2.y), a4[5], part); \
        part = fmaf(e3.x, a6[6], part); part = fmaf(fabsf(e3.x), a4[6], part); \
        part = fmaf(e3.y, a6[7], part); part = fmaf(fabsf(e3.y), a4[7], part); \
        _Pragma("unroll")                                                      \
        for (int k = 1; k < 16; k <<= 1) part += __shfl_xor(part, k);          \
        float wg = vld ? __expf(part) : 0.f;                                   \
        ssum += wg;                                                            \
        f32x2 wg2 = {wg, wg};                                                  \
        pk_fma_acc(acc2[0], wg2, u0);                                          \
        pk_fma_acc(acc2[1], wg2, u1);                                          \
        pk_fma_acc(acc2[2], wg2, u2);                                          \
        pk_fma_acc(acc2[3], wg2, u3);                                          \
      }
      GAT1_STEP(0, cAa, cAb)
      GAT1_STEP(1, cBa, cBb)
#undef GAT1_STEP
    }
  }
  // merge the 4 groups
  float accf[8] = {acc2[0].x, acc2[0].y, acc2[1].x, acc2[1].y,
                   acc2[2].x, acc2[2].y, acc2[3].x, acc2[3].y};
#pragma unroll
  for (int j = 0; j < 8; j++) {
    accf[j] += __shfl_xor(accf[j], 16);
    accf[j] += __shfl_xor(accf[j], 32);
  }
  ssum += __shfl_xor(ssum, 16);
  ssum += __shfl_xor(ssum, 32);
  if (lane < 16) {
    float inv = ssum > 0.f ? 1.f / ssum : 0.f;
    float4 o0 = make_float4(accf[0] * inv, accf[1] * inv, accf[2] * inv, accf[3] * inv);
    float4 o1 = make_float4(accf[4] * inv, accf[5] * inv, accf[6] * inv, accf[7] * inv);
    ushort4 hv0, lv0, hv1, lv1;
    split4(o0, hv0, lv0);
    split4(o1, hv1, lv1);
    *(ushort4*)(outh + (size_t)v * HD + off) = hv0;
    *(ushort4*)(outh + (size_t)v * HD + off + 4) = hv1;
    *(ushort4*)(outl + (size_t)v * HD + off) = lv0;
    *(ushort4*)(outl + (size_t)v * HD + off + 4) = lv1;
  }
}

// ---------------- layer 2 fused: one wave per node, packed fp32 ----------------
__global__ __launch_bounds__(64) void fused_gat2(
    const float* __restrict__ hs, const float* __restrict__ hd,
    const float* __restrict__ attn, const int* __restrict__ row_off,
    const int* __restrict__ srcl, float* __restrict__ out) {
  int lane = threadIdx.x, grp = lane >> 4, sl = lane & 15;
  int v = blockIdx.x;
  int start = row_off[v];
  int deg = row_off[v + 1] - start;

  const float* ap = attn + sl * 8;
  const float* hp = hd + (size_t)v * DD + sl * 8;
  float4 a0 = *(const float4*)ap, a1 = *(const float4*)(ap + 4);
  float4 g0 = *(const float4*)hp, g1 = *(const float4*)(hp + 4);
  float areg[8] = {a0.x, a0.y, a0.z, a0.w, a1.x, a1.y, a1.z, a1.w};
  float a6[8], a4[8];
#pragma unroll
  for (int j = 0; j < 8; j++) { a6[j] = 0.6f * areg[j]; a4[j] = 0.4f * areg[j]; }
  f32x2 hd2[4] = {{g0.x, g0.y}, {g0.z, g0.w}, {g1.x, g1.y}, {g1.z, g1.w}};
  const float* hsl = hs + sl * 8;

  float ssum = 0.f;
  f32x2 acc2[4] = {{0.f, 0.f}, {0.f, 0.f}, {0.f, 0.f}, {0.f, 0.f}};

  float4 c0a = {0,0,0,0}, c0b = {0,0,0,0}, c1a = {0,0,0,0}, c1b = {0,0,0,0};
  if (grp < deg) { const float* p = hsl + (size_t)srcl[start + grp] * DD; c0a = *(const float4*)p; c0b = *(const float4*)(p + 4); }
  if (grp + 4 < deg) { const float* p = hsl + (size_t)srcl[start + grp + 4] * DD; c1a = *(const float4*)p; c1b = *(const float4*)(p + 4); }

  for (int i = grp; i < deg; i += 8) {
#define GAT2_STEP(COND, NEXTI, CA, CB)                                         \
    { bool vld = (COND);                                                       \
      f32x2 u0 = {CA.x, CA.y}, u1 = {CA.z, CA.w};                              \
      f32x2 u2 = {CB.x, CB.y}, u3 = {CB.z, CB.w};                              \
      if ((NEXTI) < deg) {                                                     \
        const float* p = hsl + (size_t)srcl[start + (NEXTI)] * DD;             \
        CA = *(const float4*)p; CB = *(const float4*)(p + 4);                  \
      }                                                                        \
      f32x2 e0 = pk_add(u0, hd2[0]);                                           \
      f32x2 e1 = pk_add(u1, hd2[1]);                                           \
      f32x2 e2 = pk_add(u2, hd2[2]);                                           \
      f32x2 e3 = pk_add(u3, hd2[3]);                                           \
      float part = 0.f;                                                        \
      part = fmaf(e0.x, a6[0], part); part = fmaf(fabsf(e0.x), a4[0], part);   \
      part = fmaf(e0.y, a6[1], part); part = fmaf(fabsf(e0.y), a4[1], part);   \
      part = fmaf(e1.x, a6[2], part); part = fmaf(fabsf(e1.x), a4[2], part);   \
      part = fmaf(e1.y, a6[3], part); part = fmaf(fabsf(e1.y), a4[3], part);   \
      part = fmaf(e2.x, a6[4], part); part = fmaf(fabsf(e2.x), a4[4], part);   \
      part = fmaf(e2.y, a6[5], part); part = fmaf(fabsf(e2.y), a4[5], part);   \
      part = fmaf(e3.x, a6[6], part); part = fmaf(fabsf(e3.x), a4[6], part);   \
      part = fmaf(e3.y, a6[7], part); part = fmaf(fabsf(e3.y), a4[7], part);   \
      _Pragma("unroll")                                                        \
      for (int k = 1; k < 16; k <<= 1) part += __shfl_xor(part, k);            \
      float wg = vld ? __expf(part) : 0.f;                                     \
      ssum += wg;                                                              \
      f32x2 wg2 = {wg, wg};                                                    \
      pk_fma_acc(acc2[0], wg2, u0);                                            \
      pk_fma_acc(acc2[1], wg2, u1);                                            \
      pk_fma_acc(acc2[2], wg2, u2);                                            \
      pk_fma_acc(acc2[3], wg2, u3);                                            \
    }
    GAT2_STEP(true, i + 8, c0a, c0b)
    GAT2_STEP((i + 4) < deg, i + 12, c1a, c1b)
#undef GAT2_STEP
  }
  float accf[8] = {acc2[0].x, acc2[0].y, acc2[1].x, acc2[1].y,
                   acc2[2].x, acc2[2].y, acc2[3].x, acc2[3].y};
#pragma unroll
  for (int j = 0; j < 8; j++) {
    accf[j] += __shfl_xor(accf[j], 16);
    accf[j] += __shfl_xor(accf[j], 32);
  }
  ssum += __shfl_xor(ssum, 16);
  ssum += __shfl_xor(ssum, 32);
  float inv = ssum > 0.f ? 1.f / ssum : 0.f;
  if (lane < 16) {
    float* op = out + (size_t)v * DD + sl * 8;
    *(float4*)op = make_float4(accf[0] * inv, accf[1] * inv, accf[2] * inv, accf[3] * inv);
    *(float4*)(op + 4) = make_float4(accf[4] * inv, accf[5] * inv, accf[6] * inv, accf[7] * inv);
  }
}

// ---------------- pooling (binary search on sorted gid) + readout MLP ----------
__global__ __launch_bounds__(128) void final_kernel(
    const float* __restrict__ h2, const int* __restrict__ gid,
    const float* __restrict__ Wr1, const float* __restrict__ br1,
    const float* __restrict__ Wr2, const float* __restrict__ br2,
    float* __restrict__ out) {
  int g = blockIdx.x, t = threadIdx.x;
  int a, b;
  { int l = 0, h = N_NODES; while (l < h) { int m = (l + h) >> 1; if (gid[m] < g) l = m + 1; else h = m; } a = l; }
  { int l = a, h = N_NODES; while (l < h) { int m = (l + h) >> 1; if (gid[m] < g + 1) l = m + 1; else h = m; } b = l; }
  float s0 = 0.f, s1 = 0.f, s2 = 0.f, s3 = 0.f;
  int v = a;
  for (; v + 3 < b; v += 4) {
    s0 += h2[(size_t)(v + 0) * DD + t];
    s1 += h2[(size_t)(v + 1) * DD + t];
    s2 += h2[(size_t)(v + 2) * DD + t];
    s3 += h2[(size_t)(v + 3) * DD + t];
  }
  for (; v < b; v++) s0 += h2[(size_t)v * DD + t];
  __shared__ float hgn[128];
  float cnt = (float)(b - a);
  hgn[t] = ((s0 + s1) + (s2 + s3)) / fmaxf(cnt, 1.f);
  __syncthreads();
  if (t < 64) {
    float r = br1[t];
#pragma unroll 8
    for (int k = 0; k < 128; k++) r = fmaf(hgn[k], Wr1[k * 64 + t], r);
    r = fmaxf(r, 0.f);
    float p = r * Wr2[t];
#pragma unroll
    for (int k = 1; k < 64; k <<= 1) p += __shfl_xor(p, k);
    if (t == 0) out[g] = p + br2[0];
  }
}

extern "C" void kernel_launch(void* const* d_in, const int* in_sizes, int n_in,
                              void* d_out, int out_size, void* d_ws, size_t ws_size,
                              hipStream_t stream) {
  (void)in_sizes; (void)n_in; (void)out_size; (void)ws_size;
  const float* x     = (const float*)d_in[0];
  const float* W1s   = (const float*)d_in[1];
  const float* b1s   = (const float*)d_in[2];
  const float* W1d   = (const float*)d_in[3];
  const float* b1d   = (const float*)d_in[4];
  const float* attn1 = (const float*)d_in[5];
  const float* W2s   = (const float*)d_in[6];
  const float* b2s   = (const float*)d_in[7];
  const float* W2d   = (const float*)d_in[8];
  const float* b2d   = (const float*)d_in[9];
  const float* attn2 = (const float*)d_in[10];
  const float* Wr1   = (const float*)d_in[11];
  const float* br1   = (const float*)d_in[12];
  const float* Wr2   = (const float*)d_in[13];
  const float* br2   = (const float*)d_in[14];
  const int* src     = (const int*)d_in[15];
  const int* dst     = (const int*)d_in[16];
  const int* gid     = (const int*)d_in[17];
  float* out = (float*)d_out;

  char* ws = (char*)d_ws;
  float*  hs1     = (float*)(ws + 0);           // [10000][512] f32 (20.48 MB)
  float*  hd1     = (float*)(ws + 20480000);    // [10000][512] f32
  ushort* h1h     = (ushort*)(ws + 40960000);   // [10000][512] bf16 (10.24 MB)
  ushort* h1l     = (ushort*)(ws + 51200000);   // 10.24 MB
  ushort* xh      = (ushort*)(ws + 61440000);   // [10000][256] bf16 (5.12 MB)
  ushort* xl      = (ushort*)(ws + 66560000);   // 5.12 MB
  int*    srcl    = (int*)(ws + 71680000);      // E int (1.28 MB)
  int*    row_off = (int*)(ws + 72960000);      // N+1
  int*    cnt     = (int*)(ws + 73000064);      // N
  int*    fill    = (int*)(ws + 73040064);      // N
  ushort* b1sh    = (ushort*)(ws + 73080064);   // [512][256] bf16 (0.26 MB)
  ushort* b1sl    = (ushort*)(ws + 73342208);
  ushort* b1dh    = (ushort*)(ws + 73604352);
  ushort* b1dl    = (ushort*)(ws + 73866496);
  ushort* b2sh    = (ushort*)(ws + 74128640);   // [128][512] bf16 (0.13 MB)
  ushort* b2sl    = (ushort*)(ws + 74259712);
  ushort* b2dh    = (ushort*)(ws + 74390784);
  ushort* b2dl    = (ushort*)(ws + 74521856);
  // layer-2 reuse (hs1/hd1 regions are dead after gat1; h1h/h1l dead after gemm2)
  float*  hs2     = (float*)(ws + 0);           // [10000][128] f32 (5.12 MB)
  float*  hd2     = (float*)(ws + 5120000);
  float*  h2      = (float*)(ws + 40960000);    // over h1h after gemm2 done

  hipMemsetAsync(cnt, 0, 2 * N_NODES * 4, stream);

  hist_kernel<<<N_EDGES / 256, 256, 0, stream>>>(dst, cnt);
  scan_kernel<<<1, 1024, 0, stream>>>(cnt, row_off);
  scatter_kernel<<<N_EDGES / 256, 256, 0, stream>>>(src, dst, row_off, fill, srcl);

  // preconvert: x and weights
  split_rm<<<(N_NODES * DIM_IN / 4 + 255) / 256, 256, 0, stream>>>(x, xh, xl, N_NODES * DIM_IN / 4);
  split_tr2<<<dim3((HD * (DIM_IN / 4) + 255) / 256, 2), 256, 0, stream>>>(
      W1s, b1sh, b1sl, W1d, b1dh, b1dl, DIM_IN, HD, 9);
  split_tr2<<<dim3((DD * (HD / 4) + 255) / 256, 2), 256, 0, stream>>>(
      W2s, b2sh, b2sl, W2d, b2dh, b2dl, HD, DD, 7);

  dual_gemm_mfma<DIM_IN, HD><<<dim3(HD / 64, (N_NODES + 63) / 64), 256, 0, stream>>>(
      xh, xl, b1sh, b1sl, b1s, b1dh, b1dl, b1d, hs1, hd1, N_NODES);
  fused_gat1<<<2 * N_NODES, 64, 0, stream>>>(hs1, hd1, attn1, row_off, srcl, h1h, h1l, 0);
  fused_gat1<<<2 * N_NODES, 64, 0, stream>>>(hs1, hd1, attn1, row_off, srcl, h1h, h1l, 2);

  dual_gemm_mfma<HD, DD><<<dim3(DD / 64, (N_NODES + 63) / 64), 256, 0, stream>>>(
      h1h, h1l, b2sh, b2sl, b2s, b2dh, b2dl, b2d, hs2, hd2, N_NODES);
  fused_gat2<<<N_NODES, 64, 0, stream>>>(hs2, hd2, attn2, row_off, srcl, h2);

  final_kernel<<<GG, 128, 0, stream>>>(h2, gid, Wr1, br1, Wr2, br2, out);
}

// Round 18
// 204.112 us; speedup vs baseline: 1.0558x; 1.0558x over previous
//
#include <hip/hip_runtime.h>

typedef __attribute__((ext_vector_type(8))) short bf16x8;
typedef __attribute__((ext_vector_type(4))) float f32x4;

#define N_NODES 10000
#define N_EDGES 320000
#define DIM_IN  256
#define DD      128
#define HH      4
#define HD      512
#define GG      64

// ---------------- CSR build ----------------
__global__ void hist_kernel(const int* __restrict__ dst, int* __restrict__ cnt) {
  int e = blockIdx.x * 256 + threadIdx.x;
  atomicAdd(&cnt[dst[e]], 1);
}

__global__ void scan_kernel(const int* __restrict__ cnt, int* __restrict__ row_off) {
  __shared__ int part[1024];
  int t = threadIdx.x;
  int base = t * 10;
  int s = 0;
#pragma unroll
  for (int i = 0; i < 10; i++) { int idx = base + i; if (idx < N_NODES) s += cnt[idx]; }
  part[t] = s;
  __syncthreads();
  for (int off = 1; off < 1024; off <<= 1) {
    int v = (t >= off) ? part[t - off] : 0;
    __syncthreads();
    part[t] += v;
    __syncthreads();
  }
  int run = part[t] - s;
  for (int i = 0; i < 10; i++) {
    int idx = base + i;
    if (idx < N_NODES) { row_off[idx] = run; run += cnt[idx]; }
  }
  if (t == 1023) row_off[N_NODES] = part[1023];
}

__global__ void scatter_kernel(const int* __restrict__ src, const int* __restrict__ dst,
                               const int* __restrict__ row_off,
                               int* __restrict__ fill, int* __restrict__ srcl) {
  int e = blockIdx.x * 256 + threadIdx.x;
  int d = dst[e];
  int pos = row_off[d] + atomicAdd(&fill[d], 1);
  srcl[pos] = src[e];
}

// ---------------- split-precision helpers ----------------
__device__ inline void split4(float4 v, ushort4& h, ushort4& l) {
  uint bx = __float_as_uint(v.x), by = __float_as_uint(v.y);
  uint bz = __float_as_uint(v.z), bw = __float_as_uint(v.w);
  float rx = v.x - __uint_as_float(bx & 0xFFFF0000u);
  float ry = v.y - __uint_as_float(by & 0xFFFF0000u);
  float rz = v.z - __uint_as_float(bz & 0xFFFF0000u);
  float rw = v.w - __uint_as_float(bw & 0xFFFF0000u);
  h.x = (unsigned short)(bx >> 16); h.y = (unsigned short)(by >> 16);
  h.z = (unsigned short)(bz >> 16); h.w = (unsigned short)(bw >> 16);
  l.x = (unsigned short)(__float_as_uint(rx) >> 16);
  l.y = (unsigned short)(__float_as_uint(ry) >> 16);
  l.z = (unsigned short)(__float_as_uint(rz) >> 16);
  l.w = (unsigned short)(__float_as_uint(rw) >> 16);
}

// row-major fp32 [M][K] -> bf16 hi/lo [M][K]
__global__ __launch_bounds__(256) void split_rm(const float* __restrict__ in,
                                                ushort* __restrict__ oh,
                                                ushort* __restrict__ ol, int n4) {
  int i = blockIdx.x * 256 + threadIdx.x;
  if (i >= n4) return;
  float4 v = ((const float4*)in)[i];
  ushort4 h, l;
  split4(v, h, l);
  ((ushort4*)oh)[i] = h;
  ((ushort4*)ol)[i] = l;
}

// four fp32 [K][N] -> bf16 hi/lo transposed [N][K]; blockIdx.y selects matrix.
// y in {0,1}: K=256,N=512 (W1s,W1d); y in {2,3}: K=512,N=128 (W2s,W2d).
__global__ __launch_bounds__(256) void split_tr4(
    const float* __restrict__ in0, ushort* __restrict__ oh0, ushort* __restrict__ ol0,
    const float* __restrict__ in1, ushort* __restrict__ oh1, ushort* __restrict__ ol1,
    const float* __restrict__ in2, ushort* __restrict__ oh2, ushort* __restrict__ ol2,
    const float* __restrict__ in3, ushort* __restrict__ oh3, ushort* __restrict__ ol3) {
  int m = blockIdx.y;
  const float* in;
  ushort* oh;
  ushort* ol;
  int K, N, lgN;
  if (m == 0)      { in = in0; oh = oh0; ol = ol0; K = DIM_IN; N = HD; lgN = 9; }
  else if (m == 1) { in = in1; oh = oh1; ol = ol1; K = DIM_IN; N = HD; lgN = 9; }
  else if (m == 2) { in = in2; oh = oh2; ol = ol2; K = HD; N = DD; lgN = 7; }
  else             { in = in3; oh = oh3; ol = ol3; K = HD; N = DD; lgN = 7; }
  int id = blockIdx.x * 256 + threadIdx.x;
  int n = id & (N - 1);
  int kq = id >> lgN;
  if (kq >= (K >> 2)) return;
  int k = kq * 4;
  float4 v;
  v.x = in[(size_t)(k + 0) * N + n];
  v.y = in[(size_t)(k + 1) * N + n];
  v.z = in[(size_t)(k + 2) * N + n];
  v.w = in[(size_t)(k + 3) * N + n];
  ushort4 h, l;
  split4(v, h, l);
  *(ushort4*)(oh + (size_t)n * K + k) = h;
  *(ushort4*)(ol + (size_t)n * K + k) = l;
}

// ---------------- dual GEMM via bf16x3 MFMA (register-prefetch pipelined) ------
template <int K, int NCOL>
__global__ __launch_bounds__(256) void dual_gemm_mfma(
    const ushort* __restrict__ Ahg, const ushort* __restrict__ Alg,
    const ushort* __restrict__ B1hg, const ushort* __restrict__ B1lg,
    const float* __restrict__ bias1,
    const ushort* __restrict__ B2hg, const ushort* __restrict__ B2lg,
    const float* __restrict__ bias2,
    float* __restrict__ C1, float* __restrict__ C2, int M) {
  __shared__ ushort Ah[64][40], Al[64][40];
  __shared__ ushort B1h[64][40], B1l[64][40], B2h[64][40], B2l[64][40];
  int t = threadIdx.x;
  int lane = t & 63, wv = t >> 6;
  int wr = wv >> 1, wc = wv & 1;
  int l15 = lane & 15, l16 = lane >> 4;
  int col0 = blockIdx.x * 64, m0 = blockIdx.y * 64;

  int sr = t >> 2;           // staging row (A) / col (B): 0..63
  int sk = (t & 3) * 8;      // staging k offset: 0,8,16,24
  bool arow_ok = (m0 + sr) < M;
  const ushort* pAh = Ahg + (size_t)(m0 + sr) * K + sk;
  const ushort* pAl = Alg + (size_t)(m0 + sr) * K + sk;
  const ushort* pB1h = B1hg + (size_t)(col0 + sr) * K + sk;
  const ushort* pB1l = B1lg + (size_t)(col0 + sr) * K + sk;
  const ushort* pB2h = B2hg + (size_t)(col0 + sr) * K + sk;
  const ushort* pB2l = B2lg + (size_t)(col0 + sr) * K + sk;

  f32x4 zero = {0.f, 0.f, 0.f, 0.f};
  f32x4 acc1[2][2], acc2[2][2];
#pragma unroll
  for (int i = 0; i < 2; i++)
#pragma unroll
    for (int j = 0; j < 2; j++) { acc1[i][j] = zero; acc2[i][j] = zero; }

  uint4 vah, val, v1h, v1l, v2h, v2l;
#define LOADK(KO)                                                            \
  vah = arow_ok ? *(const uint4*)(pAh + (KO)) : make_uint4(0u, 0u, 0u, 0u);  \
  val = arow_ok ? *(const uint4*)(pAl + (KO)) : make_uint4(0u, 0u, 0u, 0u);  \
  v1h = *(const uint4*)(pB1h + (KO));                                        \
  v1l = *(const uint4*)(pB1l + (KO));                                        \
  v2h = *(const uint4*)(pB2h + (KO));                                        \
  v2l = *(const uint4*)(pB2l + (KO));
  LOADK(0)
  for (int k0 = 0; k0 < K; k0 += 32) {
    __syncthreads();
    *(uint4*)&Ah[sr][sk] = vah;
    *(uint4*)&Al[sr][sk] = val;
    *(uint4*)&B1h[sr][sk] = v1h;
    *(uint4*)&B1l[sr][sk] = v1l;
    *(uint4*)&B2h[sr][sk] = v2h;
    *(uint4*)&B2l[sr][sk] = v2l;
    __syncthreads();
    if (k0 + 32 < K) { LOADK(k0 + 32) }   // issue next-tile loads before MFMA
#pragma unroll
    for (int cb = 0; cb < 2; cb++) {
      int bc = wc * 32 + cb * 16 + l15;
      bf16x8 b1hf = *(const bf16x8*)&B1h[bc][l16 * 8];
      bf16x8 b1lf = *(const bf16x8*)&B1l[bc][l16 * 8];
      bf16x8 b2hf = *(const bf16x8*)&B2h[bc][l16 * 8];
      bf16x8 b2lf = *(const bf16x8*)&B2l[bc][l16 * 8];
#pragma unroll
      for (int rb = 0; rb < 2; rb++) {
        int arw = wr * 32 + rb * 16 + l15;
        bf16x8 ahf = *(const bf16x8*)&Ah[arw][l16 * 8];
        bf16x8 alf = *(const bf16x8*)&Al[arw][l16 * 8];
        acc1[rb][cb] = __builtin_amdgcn_mfma_f32_16x16x32_bf16(ahf, b1hf, acc1[rb][cb], 0, 0, 0);
        acc1[rb][cb] = __builtin_amdgcn_mfma_f32_16x16x32_bf16(ahf, b1lf, acc1[rb][cb], 0, 0, 0);
        acc1[rb][cb] = __builtin_amdgcn_mfma_f32_16x16x32_bf16(alf, b1hf, acc1[rb][cb], 0, 0, 0);
        acc2[rb][cb] = __builtin_amdgcn_mfma_f32_16x16x32_bf16(ahf, b2hf, acc2[rb][cb], 0, 0, 0);
        acc2[rb][cb] = __builtin_amdgcn_mfma_f32_16x16x32_bf16(ahf, b2lf, acc2[rb][cb], 0, 0, 0);
        acc2[rb][cb] = __builtin_amdgcn_mfma_f32_16x16x32_bf16(alf, b2hf, acc2[rb][cb], 0, 0, 0);
      }
    }
  }
#undef LOADK
#pragma unroll
  for (int rb = 0; rb < 2; rb++) {
#pragma unroll
    for (int cb = 0; cb < 2; cb++) {
      int row = m0 + wr * 32 + rb * 16 + l16 * 4;
      int col = col0 + wc * 32 + cb * 16 + l15;
      float bb1 = bias1[col], bb2 = bias2[col];
#pragma unroll
      for (int rr = 0; rr < 4; rr++) {
        if (row + rr < M) {
          C1[(size_t)(row + rr) * NCOL + col] = acc1[rb][cb][rr] + bb1;
          C2[(size_t)(row + rr) * NCOL + col] = acc2[rb][cb][rr] + bb2;
        }
      }
    }
  }
}

// ---------------- layer 1 fused: XCD-pinned head-slices, 4 edges per step ------
// One wave per block (64 thr, grid 4N): block b -> slice = b & 3, node = b >> 2.
// Wave = 4 x 16-lane groups; group owns one edge; lane covers 8 floats.
// leaky(x) = 0.6x + 0.4|x| -> add + 2 fma (abs is a free VOP3 modifier).
// EXEC-SAFETY: all __shfl on myidx execute unconditionally (clamped index).
__global__ __launch_bounds__(64) void fused_gat1(
    const float* __restrict__ hs, const float* __restrict__ hd,
    const float* __restrict__ attn, const int* __restrict__ row_off,
    const int* __restrict__ srcl,
    ushort* __restrict__ outh, ushort* __restrict__ outl) {
  int lane = threadIdx.x;
  int slice = blockIdx.x & 3;
  int v = blockIdx.x >> 2;
  int grp = lane >> 4, sl = lane & 15;
  int off = slice * 128 + sl * 8;
  int start = row_off[v];
  int deg = row_off[v + 1] - start;

  const float* ap = attn + off;
  const float* hp = hd + (size_t)v * HD + off;
  float4 a0 = *(const float4*)ap, a1 = *(const float4*)(ap + 4);
  float4 g0 = *(const float4*)hp, g1 = *(const float4*)(hp + 4);
  float areg[8] = {a0.x, a0.y, a0.z, a0.w, a1.x, a1.y, a1.z, a1.w};
  float hdreg[8] = {g0.x, g0.y, g0.z, g0.w, g1.x, g1.y, g1.z, g1.w};
  float a6[8], a4[8];
#pragma unroll
  for (int j = 0; j < 8; j++) { a6[j] = 0.6f * areg[j]; a4[j] = 0.4f * areg[j]; }
  const float* hsl = hs + off;

  float ssum = 0.f;
  float acc[8] = {0.f, 0.f, 0.f, 0.f, 0.f, 0.f, 0.f, 0.f};

  for (int base = 0; base < deg; base += 64) {
    int nc = deg - base; nc = nc < 64 ? nc : 64;
    // one coalesced index load per 64-edge chunk
    int myidx = (lane < nc) ? srcl[start + base + lane] : 0;

    // 2-deep pipeline: buffer A = edges i0+grp, buffer B = edges i0+4+grp
    float4 cAa = {0,0,0,0}, cAb = {0,0,0,0}, cBa = {0,0,0,0}, cBb = {0,0,0,0};
    {
      int eA = grp, eB = grp + 4;
      int idxA = __shfl(myidx, eA < nc ? eA : 0);   // unconditional shfl
      int idxB = __shfl(myidx, eB < nc ? eB : 0);   // unconditional shfl
      if (eA < nc) { const float* p = hsl + (size_t)idxA * HD; cAa = *(const float4*)p; cAb = *(const float4*)(p + 4); }
      if (eB < nc) { const float* p = hsl + (size_t)idxB * HD; cBa = *(const float4*)p; cBb = *(const float4*)(p + 4); }
    }

    for (int i0 = 0; i0 < nc; i0 += 8) {
#define GAT1_STEP(S, CA, CB)                                                   \
      { int e = i0 + 4 * S + grp;                                              \
        int nx = i0 + 8 + 4 * S + grp;                                         \
        int nidx = __shfl(myidx, nx < nc ? nx : 0);  /* unconditional shfl */  \
        bool vld = e < nc;                                                     \
        float u[8] = {CA.x, CA.y, CA.z, CA.w, CB.x, CB.y, CB.z, CB.w};         \
        if (nx < nc) {                                                         \
          const float* p = hsl + (size_t)nidx * HD;                            \
          CA = *(const float4*)p; CB = *(const float4*)(p + 4);                \
        }                                                                      \
        float part = 0.f;                                                      \
        _Pragma("unroll")                                                      \
        for (int j = 0; j < 8; j++) {                                          \
          float ee = u[j] + hdreg[j];                                          \
          part = fmaf(ee, a6[j], part);                                        \
          part = fmaf(fabsf(ee), a4[j], part);                                 \
        }                                                                      \
        _Pragma("unroll")                                                      \
        for (int k = 1; k < 16; k <<= 1) part += __shfl_xor(part, k);          \
        float wg = vld ? __expf(part) : 0.f;                                   \
        ssum += wg;                                                            \
        _Pragma("unroll")                                                      \
        for (int j = 0; j < 8; j++) acc[j] = fmaf(wg, u[j], acc[j]);           \
      }
      GAT1_STEP(0, cAa, cAb)
      GAT1_STEP(1, cBa, cBb)
#undef GAT1_STEP
    }
  }
  // merge the 4 groups
#pragma unroll
  for (int j = 0; j < 8; j++) {
    acc[j] += __shfl_xor(acc[j], 16);
    acc[j] += __shfl_xor(acc[j], 32);
  }
  ssum += __shfl_xor(ssum, 16);
  ssum += __shfl_xor(ssum, 32);
  if (lane < 16) {
    float inv = ssum > 0.f ? 1.f / ssum : 0.f;
    float4 o0 = make_float4(acc[0] * inv, acc[1] * inv, acc[2] * inv, acc[3] * inv);
    float4 o1 = make_float4(acc[4] * inv, acc[5] * inv, acc[6] * inv, acc[7] * inv);
    ushort4 hv0, lv0, hv1, lv1;
    split4(o0, hv0, lv0);
    split4(o1, hv1, lv1);
    *(ushort4*)(outh + (size_t)v * HD + off) = hv0;
    *(ushort4*)(outh + (size_t)v * HD + off + 4) = hv1;
    *(ushort4*)(outl + (size_t)v * HD + off) = lv0;
    *(ushort4*)(outl + (size_t)v * HD + off + 4) = lv1;
  }
}

// ---------------- layer 2 fused: one wave per node, 4 x 16-lane groups, 2-deep -
__global__ __launch_bounds__(64) void fused_gat2(
    const float* __restrict__ hs, const float* __restrict__ hd,
    const float* __restrict__ attn, const int* __restrict__ row_off,
    const int* __restrict__ srcl, float* __restrict__ out) {
  int lane = threadIdx.x, grp = lane >> 4, sl = lane & 15;
  int v = blockIdx.x;
  int start = row_off[v];
  int deg = row_off[v + 1] - start;

  const float* ap = attn + sl * 8;
  const float* hp = hd + (size_t)v * DD + sl * 8;
  float4 a0 = *(const float4*)ap, a1 = *(const float4*)(ap + 4);
  float4 g0 = *(const float4*)hp, g1 = *(const float4*)(hp + 4);
  float areg[8] = {a0.x, a0.y, a0.z, a0.w, a1.x, a1.y, a1.z, a1.w};
  float hdreg[8] = {g0.x, g0.y, g0.z, g0.w, g1.x, g1.y, g1.z, g1.w};
  float a6[8], a4[8];
#pragma unroll
  for (int j = 0; j < 8; j++) { a6[j] = 0.6f * areg[j]; a4[j] = 0.4f * areg[j]; }
  const float* hsl = hs + sl * 8;

  float ssum = 0.f;
  float acc[8] = {0.f, 0.f, 0.f, 0.f, 0.f, 0.f, 0.f, 0.f};

  float4 c0a = {0,0,0,0}, c0b = {0,0,0,0}, c1a = {0,0,0,0}, c1b = {0,0,0,0};
  if (grp < deg) { const float* p = hsl + (size_t)srcl[start + grp] * DD; c0a = *(const float4*)p; c0b = *(const float4*)(p + 4); }
  if (grp + 4 < deg) { const float* p = hsl + (size_t)srcl[start + grp + 4] * DD; c1a = *(const float4*)p; c1b = *(const float4*)(p + 4); }

  for (int i = grp; i < deg; i += 8) {
    float u0[8] = {c0a.x, c0a.y, c0a.z, c0a.w, c0b.x, c0b.y, c0b.z, c0b.w};
    float u1[8] = {c1a.x, c1a.y, c1a.z, c1a.w, c1b.x, c1b.y, c1b.z, c1b.w};
    bool have1 = (i + 4) < deg;
    if (i + 8 < deg) { const float* p = hsl + (size_t)srcl[start + i + 8] * DD; c0a = *(const float4*)p; c0b = *(const float4*)(p + 4); }
    if (i + 12 < deg) { const float* p = hsl + (size_t)srcl[start + i + 12] * DD; c1a = *(const float4*)p; c1b = *(const float4*)(p + 4); }
    float part0 = 0.f, part1 = 0.f;
#pragma unroll
    for (int j = 0; j < 8; j++) {
      float e0 = u0[j] + hdreg[j];
      part0 = fmaf(e0, a6[j], part0);
      part0 = fmaf(fabsf(e0), a4[j], part0);
      float e1 = u1[j] + hdreg[j];
      part1 = fmaf(e1, a6[j], part1);
      part1 = fmaf(fabsf(e1), a4[j], part1);
    }
#pragma unroll
    for (int k = 1; k < 16; k <<= 1) {
      part0 += __shfl_xor(part0, k);
      part1 += __shfl_xor(part1, k);
    }
    float wg0 = __expf(part0);
    float wg1 = have1 ? __expf(part1) : 0.f;
    ssum += wg0 + wg1;
#pragma unroll
    for (int j = 0; j < 8; j++)
      acc[j] = fmaf(wg0, u0[j], fmaf(wg1, u1[j], acc[j]));
  }
#pragma unroll
  for (int j = 0; j < 8; j++) {
    acc[j] += __shfl_xor(acc[j], 16);
    acc[j] += __shfl_xor(acc[j], 32);
  }
  ssum += __shfl_xor(ssum, 16);
  ssum += __shfl_xor(ssum, 32);
  float inv = ssum > 0.f ? 1.f / ssum : 0.f;
  if (lane < 16) {
    float* op = out + (size_t)v * DD + sl * 8;
    *(float4*)op = make_float4(acc[0] * inv, acc[1] * inv, acc[2] * inv, acc[3] * inv);
    *(float4*)(op + 4) = make_float4(acc[4] * inv, acc[5] * inv, acc[6] * inv, acc[7] * inv);
  }
}

// ---------------- pooling (binary search on sorted gid) + readout MLP ----------
__global__ __launch_bounds__(128) void final_kernel(
    const float* __restrict__ h2, const int* __restrict__ gid,
    const float* __restrict__ Wr1, const float* __restrict__ br1,
    const float* __restrict__ Wr2, const float* __restrict__ br2,
    float* __restrict__ out) {
  int g = blockIdx.x, t = threadIdx.x;
  int a, b;
  { int l = 0, h = N_NODES; while (l < h) { int m = (l + h) >> 1; if (gid[m] < g) l = m + 1; else h = m; } a = l; }
  { int l = a, h = N_NODES; while (l < h) { int m = (l + h) >> 1; if (gid[m] < g + 1) l = m + 1; else h = m; } b = l; }
  float s0 = 0.f, s1 = 0.f, s2 = 0.f, s3 = 0.f;
  int v = a;
  for (; v + 3 < b; v += 4) {
    s0 += h2[(size_t)(v + 0) * DD + t];
    s1 += h2[(size_t)(v + 1) * DD + t];
    s2 += h2[(size_t)(v + 2) * DD + t];
    s3 += h2[(size_t)(v + 3) * DD + t];
  }
  for (; v < b; v++) s0 += h2[(size_t)v * DD + t];
  __shared__ float hgn[128];
  float cnt = (float)(b - a);
  hgn[t] = ((s0 + s1) + (s2 + s3)) / fmaxf(cnt, 1.f);
  __syncthreads();
  if (t < 64) {
    float r = br1[t];
#pragma unroll 8
    for (int k = 0; k < 128; k++) r = fmaf(hgn[k], Wr1[k * 64 + t], r);
    r = fmaxf(r, 0.f);
    float p = r * Wr2[t];
#pragma unroll
    for (int k = 1; k < 64; k <<= 1) p += __shfl_xor(p, k);
    if (t == 0) out[g] = p + br2[0];
  }
}

extern "C" void kernel_launch(void* const* d_in, const int* in_sizes, int n_in,
                              void* d_out, int out_size, void* d_ws, size_t ws_size,
                              hipStream_t stream) {
  (void)in_sizes; (void)n_in; (void)out_size; (void)ws_size;
  const float* x     = (const float*)d_in[0];
  const float* W1s   = (const float*)d_in[1];
  const float* b1s   = (const float*)d_in[2];
  const float* W1d   = (const float*)d_in[3];
  const float* b1d   = (const float*)d_in[4];
  const float* attn1 = (const float*)d_in[5];
  const float* W2s   = (const float*)d_in[6];
  const float* b2s   = (const float*)d_in[7];
  const float* W2d   = (const float*)d_in[8];
  const float* b2d   = (const float*)d_in[9];
  const float* attn2 = (const float*)d_in[10];
  const float* Wr1   = (const float*)d_in[11];
  const float* br1   = (const float*)d_in[12];
  const float* Wr2   = (const float*)d_in[13];
  const float* br2   = (const float*)d_in[14];
  const int* src     = (const int*)d_in[15];
  const int* dst     = (const int*)d_in[16];
  const int* gid     = (const int*)d_in[17];
  float* out = (float*)d_out;

  char* ws = (char*)d_ws;
  float*  hs1     = (float*)(ws + 0);           // [10000][512] f32 (20.48 MB)
  float*  hd1     = (float*)(ws + 20480000);    // [10000][512] f32
  ushort* h1h     = (ushort*)(ws + 40960000);   // [10000][512] bf16 (10.24 MB)
  ushort* h1l     = (ushort*)(ws + 51200000);   // 10.24 MB
  ushort* xh      = (ushort*)(ws + 61440000);   // [10000][256] bf16 (5.12 MB)
  ushort* xl      = (ushort*)(ws + 66560000);   // 5.12 MB
  int*    srcl    = (int*)(ws + 71680000);      // E int (1.28 MB)
  int*    row_off = (int*)(ws + 72960000);      // N+1
  int*    cnt     = (int*)(ws + 73000064);      // N
  int*    fill    = (int*)(ws + 73040064);      // N
  ushort* b1sh    = (ushort*)(ws + 73080064);   // [512][256] bf16 (0.26 MB)
  ushort* b1sl    = (ushort*)(ws + 73342208);
  ushort* b1dh    = (ushort*)(ws + 73604352);
  ushort* b1dl    = (ushort*)(ws + 73866496);
  ushort* b2sh    = (ushort*)(ws + 74128640);   // [128][512] bf16 (0.13 MB)
  ushort* b2sl    = (ushort*)(ws + 74259712);
  ushort* b2dh    = (ushort*)(ws + 74390784);
  ushort* b2dl    = (ushort*)(ws + 74521856);
  // layer-2 reuse (hs1/hd1 regions are dead after gat1; h1h/h1l dead after gemm2)
  float*  hs2     = (float*)(ws + 0);           // [10000][128] f32 (5.12 MB)
  float*  hd2     = (float*)(ws + 5120000);
  float*  h2      = (float*)(ws + 40960000);    // over h1h after gemm2 done

  hipMemsetAsync(cnt, 0, 2 * N_NODES * 4, stream);

  hist_kernel<<<N_EDGES / 256, 256, 0, stream>>>(dst, cnt);
  scan_kernel<<<1, 1024, 0, stream>>>(cnt, row_off);
  scatter_kernel<<<N_EDGES / 256, 256, 0, stream>>>(src, dst, row_off, fill, srcl);

  // preconvert: x and all four weight matrices (one launch each)
  split_rm<<<(N_NODES * DIM_IN / 4 + 255) / 256, 256, 0, stream>>>(x, xh, xl, N_NODES * DIM_IN / 4);
  split_tr4<<<dim3((HD * (DIM_IN / 4) + 255) / 256, 4), 256, 0, stream>>>(
      W1s, b1sh, b1sl, W1d, b1dh, b1dl, W2s, b2sh, b2sl, W2d, b2dh, b2dl);

  dual_gemm_mfma<DIM_IN, HD><<<dim3(HD / 64, (N_NODES + 63) / 64), 256, 0, stream>>>(
      xh, xl, b1sh, b1sl, b1s, b1dh, b1dl, b1d, hs1, hd1, N_NODES);
  fused_gat1<<<4 * N_NODES, 64, 0, stream>>>(hs1, hd1, attn1, row_off, srcl, h1h, h1l);

  dual_gemm_mfma<HD, DD><<<dim3(DD / 64, (N_NODES + 63) / 64), 256, 0, stream>>>(
      h1h, h1l, b2sh, b2sl, b2s, b2dh, b2dl, b2d, hs2, hd2, N_NODES);
  fused_gat2<<<N_NODES, 64, 0, stream>>>(hs2, hd2, attn2, row_off, srcl, h2);

  final_kernel<<<GG, 128, 0, stream>>>(h2, gid, Wr1, br1, Wr2, br2, out);
}